// Round 7
// baseline (236.813 us; speedup 1.0000x reference)
//
#include <hip/hip_runtime.h>
#include <hip/hip_bf16.h>

#define N_ATOMS 2048
#define F_DIM   64
#define H_DIM   128
#define K_DIM   256
#define KD      8192
#define BM 64
#define BN 32
#define BK 128
#define NT (KD / BK)   // 64 K-steps

typedef __attribute__((ext_vector_type(8))) short short8;
typedef __attribute__((ext_vector_type(4))) float f32x4;
typedef __attribute__((ext_vector_type(8))) unsigned short ushort8v;

static __device__ __forceinline__ unsigned short f2bf(float x) {
  unsigned int u = __float_as_uint(x);
  u += 0x7fff + ((u >> 16) & 1);           // round-to-nearest-even
  return (unsigned short)(u >> 16);
}

// ---------------------------------------------------------------------------
// Fat kernel: blocks 0..511 transpose+convert W into swizzled 8KB tiles;
// blocks 512..2559 compute adj_exp rows (1 GiB stream, HBM-bound).
// ---------------------------------------------------------------------------
__global__ __launch_bounds__(256) void fused_prep_kernel(
    const float* __restrict__ dist_adj,
    const float* __restrict__ dist_exp,
    const float* __restrict__ W,
    float* __restrict__ adj_exp,
    unsigned short* __restrict__ Wt) {
  __shared__ __align__(16) char smem[17408];
  const int t = threadIdx.x;

  if (blockIdx.x < 512) {
    // ---- wt path: 64 fh-rows x 64 cols per block (unchanged) ----
    const int q    = blockIdx.x;
    const int cb   = q >> 7;          // 0..3  (64-col group)
    const int kb   = (q >> 1) & 63;   // 0..63 (K-step)
    const int half = q & 1;           // fh half (64 rows)
    float (*tile)[68] = (float(*)[68])smem;

    {
      const int r0 = t >> 4;          // 0..15
      const int c4 = (t & 15) * 4;    // 0..60
      #pragma unroll
      for (int i = 0; i < 4; ++i) {
        const int r = i * 16 + r0;
        f32x4 v = *(const f32x4*)(W + (size_t)(kb * 128 + half * 64 + r) * K_DIM + cb * 64 + c4);
        tile[r][c4 + 0] = v[0]; tile[r][c4 + 1] = v[1];
        tile[r][c4 + 2] = v[2]; tile[r][c4 + 3] = v[3];
      }
    }
    __syncthreads();
    {
      char* outb = (char*)Wt;
      #pragma unroll
      for (int j = 0; j < 2; ++j) {
        const int lin  = t * 32 + j * 16;          // 0..8191
        const int cc   = lin >> 7;                 // 0..63 (col in 64-group)
        const int w128 = lin & 127;
        const int k0   = (w128 ^ ((cc & 7) << 4)) >> 1;   // local fh row (mult of 8)
        ushort8v v;
        #pragma unroll
        for (int e = 0; e < 8; ++e) v[e] = f2bf(tile[k0 + e][cc]);
        const size_t tb = (size_t)(((cb * 2 + (cc >> 5)) << 6) | kb) * 8192;
        *(ushort8v*)(outb + tb + (cc & 31) * 256 + half * 128 + w128) = v;
      }
    }
  } else {
    // ---- adj path: adj_exp[m][f] = sum_n dist_adj[m][n]*dist_exp[m][n][f] ----
    const int m  = blockIdx.x - 512;
    const int f4 = t & 15;
    const int ng = t >> 4;

    // transposed coefficient table: arowT[g][i] = dist_adj[m][g + 16*i]
    float (*arowT)[132] = (float(*)[132])smem;               // 16*132*4 = 8448 B
    f32x4* red = (f32x4*)(smem + 8448);                      // 4 KB

    {
      const f32x4* src = (const f32x4*)(dist_adj + (size_t)m * N_ATOMS);
      #pragma unroll
      for (int i = 0; i < 2; ++i) {
        const int idx = i * 256 + t;                         // 512 float4 total
        f32x4 v = src[idx];
        const int j0 = idx * 4;
        #pragma unroll
        for (int e = 0; e < 4; ++e) arowT[(j0 + e) & 15][(j0 + e) >> 4] = v[e];
      }
    }
    __syncthreads();

    const float* __restrict__ base = dist_exp + (size_t)m * N_ATOMS * F_DIM + f4 * 4;
    f32x4 acc = {0.f, 0.f, 0.f, 0.f};
    #pragma unroll 2
    for (int i4 = 0; i4 < 32; ++i4) {
      f32x4 a4 = *(const f32x4*)&arowT[ng][i4 * 4];          // broadcast, 1 ds_read_b128
      #pragma unroll
      for (int j = 0; j < 4; ++j) {
        const int n = ng + i4 * 64 + j * 16;
        f32x4 v = *(const f32x4*)(base + (size_t)n * F_DIM);
        acc += a4[j] * v;
      }
    }

    red[ng * 16 + f4] = acc;
    __syncthreads();
    if (t < 16) {
      f32x4 s = red[t];
      #pragma unroll
      for (int g = 1; g < 16; ++g) s += red[g * 16 + t];
      *(f32x4*)(adj_exp + m * F_DIM + t * 4) = s;
    }
  }
}

// ---------------------------------------------------------------------------
// Bilinear (UNCHANGED from r6): feat[m,c] = sum_f a[m,f] * (E . W_f)[m,c].
// BM=64 x BN=32; E in registers; 4-buffer depth-2 pipeline, one barrier/step.
// ---------------------------------------------------------------------------
__global__ __launch_bounds__(256) void bilinear_kernel(
    const float* __restrict__ adj_exp,         // [2048][64]
    const float* __restrict__ emb,             // [2048][128]
    const unsigned short* __restrict__ Wt,     // tiled swizzled bf16
    const float* __restrict__ bias,            // [256]
    float* __restrict__ out) {                 // [2048][256] f32
  const int b   = blockIdx.x;
  const int wg  = (b & 7) * 32 + (b >> 3);
  const int cbt = wg >> 5;       // 0..7 (32-col panel)
  const int mb  = wg & 31;       // 0..31
  const int m0  = mb * BM;
  const int c0  = cbt * BN;

  const int t  = threadIdx.x;
  const int w  = t >> 6;
  const int l  = t & 63;
  const int lr = l & 15;
  const int lg = l >> 4;
  const int cg = w & 1;
  const int rb = (w >> 1) * 32;

  __shared__ __align__(16) unsigned short Bl[4][4096];   // 4 x 8KB tiles
  __shared__ __align__(16) float adjT[F_DIM][BM];        // [f][m] 16KB

  const char* wt_base = (const char*)Wt;
  #define STAGE_B(buf, step)                                                      \
    {                                                                             \
      const char* src = wt_base + (size_t)((cbt << 6) | (step)) * 8192;           \
      char* dstb = (char*)&Bl[(buf)][0];                                          \
      _Pragma("unroll")                                                           \
      for (int i = 0; i < 2; ++i) {                                               \
        const int chunk = w * 2 + i;                                              \
        __builtin_amdgcn_global_load_lds(                                         \
            (const __attribute__((address_space(1))) unsigned int*)(src + chunk * 1024 + l * 16), \
            (__attribute__((address_space(3))) unsigned int*)(dstb + chunk * 1024), \
            16, 0, 0);                                                            \
      }                                                                           \
    }

  STAGE_B(0, 0);
  STAGE_B(1, 1);

  short8 Ef0[4], Ef1[4];
  {
    const float* p0 = emb + (size_t)(m0 + rb + lr) * H_DIM;
    const float* p1 = emb + (size_t)(m0 + rb + 16 + lr) * H_DIM;
    #pragma unroll
    for (int ks = 0; ks < 4; ++ks) {
      f32x4 u0 = *(const f32x4*)(p0 + ks * 32 + lg * 8);
      f32x4 u1 = *(const f32x4*)(p0 + ks * 32 + lg * 8 + 4);
      f32x4 v0 = *(const f32x4*)(p1 + ks * 32 + lg * 8);
      f32x4 v1 = *(const f32x4*)(p1 + ks * 32 + lg * 8 + 4);
      short8 e0, e1;
      #pragma unroll
      for (int i = 0; i < 4; ++i) {
        e0[i] = (short)f2bf(u0[i]); e0[4 + i] = (short)f2bf(u1[i]);
        e1[i] = (short)f2bf(v0[i]); e1[4 + i] = (short)f2bf(v1[i]);
      }
      Ef0[ks] = e0; Ef1[ks] = e1;
    }
  }
  {
    const int r  = t & 63;
    const int fb = (t >> 6) * 16;
    #pragma unroll
    for (int i = 0; i < 4; ++i) {
      f32x4 a = *(const f32x4*)(adj_exp + (size_t)(m0 + r) * F_DIM + fb + i * 4);
      adjT[fb + i * 4 + 0][r] = a[0]; adjT[fb + i * 4 + 1][r] = a[1];
      adjT[fb + i * 4 + 2][r] = a[2]; adjT[fb + i * 4 + 3][r] = a[3];
    }
  }
  __syncthreads();

  f32x4 facc0 = {0.f, 0.f, 0.f, 0.f};
  f32x4 facc1 = {0.f, 0.f, 0.f, 0.f};
  const int c_loc = cg * 16 + lr;
  const int bswz  = (lr & 7) << 4;

  #pragma unroll 1
  for (int ts = 0; ts < NT; ++ts) {
    if (ts + 2 < NT) {
      STAGE_B((ts + 2) & 3, ts + 2);
      asm volatile("s_waitcnt vmcnt(4)" ::: "memory");
    } else if (ts + 2 == NT) {
      asm volatile("s_waitcnt vmcnt(2)" ::: "memory");
    } else {
      asm volatile("s_waitcnt vmcnt(0)" ::: "memory");
    }
    __builtin_amdgcn_s_barrier();
    asm volatile("" ::: "memory");

    const char* Bbase = (const char*)&Bl[ts & 3][0];
    f32x4 t0 = {0.f, 0.f, 0.f, 0.f};
    f32x4 t1 = {0.f, 0.f, 0.f, 0.f};
    #pragma unroll
    for (int ks = 0; ks < 4; ++ks) {
      const int boff = c_loc * 256 + ((ks * 64 + lg * 16) ^ bswz);
      short8 bf = *(const short8*)(Bbase + boff);
      t0 = __builtin_amdgcn_mfma_f32_16x16x32_bf16(Ef0[ks], bf, t0, 0, 0, 0);
      t1 = __builtin_amdgcn_mfma_f32_16x16x32_bf16(Ef1[ks], bf, t1, 0, 0, 0);
    }
    f32x4 a0 = *(const f32x4*)&adjT[ts][rb + lg * 4];
    f32x4 a1 = *(const f32x4*)&adjT[ts][rb + 16 + lg * 4];
    facc0 += a0 * t0;
    facc1 += a1 * t1;
  }
  #undef STAGE_B

  const int col = c0 + c_loc;
  const float bb = bias[col];
  #pragma unroll
  for (int r = 0; r < 4; ++r) {
    const int row0 = m0 + rb + lg * 4 + r;
    float x0  = facc0[r];
    float sp0 = (x0 > 20.f) ? x0 : ((x0 < -20.f) ? __expf(x0) : log1pf(__expf(x0)));
    out[(size_t)row0 * K_DIM + col] = sp0 + bb;
    const int row1 = row0 + 16;
    float x1  = facc1[r];
    float sp1 = (x1 > 20.f) ? x1 : ((x1 < -20.f) ? __expf(x1) : log1pf(__expf(x1)));
    out[(size_t)row1 * K_DIM + col] = sp1 + bb;
  }
}

// ---------------------------------------------------------------------------
extern "C" void kernel_launch(void* const* d_in, const int* in_sizes, int n_in,
                              void* d_out, int out_size, void* d_ws, size_t ws_size,
                              hipStream_t stream) {
  const float* dist_adj   = (const float*)d_in[0];   // [2048][2048]
  const float* dist_exp   = (const float*)d_in[1];   // [2048][2048][64]
  const float* atom_emb   = (const float*)d_in[2];   // [2048][128]
  const float* bilinear_w = (const float*)d_in[3];   // [64][128][256]
  const float* bilinear_b = (const float*)d_in[4];   // [256]
  float* out = (float*)d_out;                        // f32 [2048][256]

  float* adj_exp = (float*)d_ws;                                   // 512 KB
  unsigned short* Wt =
      (unsigned short*)((char*)d_ws + (size_t)N_ATOMS * F_DIM * sizeof(float)); // 4 MB

  hipLaunchKernelGGL(fused_prep_kernel, dim3(512 + N_ATOMS), dim3(256), 0, stream,
                     dist_adj, dist_exp, bilinear_w, adj_exp, Wt);
  hipLaunchKernelGGL(bilinear_kernel, dim3((N_ATOMS / BM) * (K_DIM / BN)), dim3(256), 0, stream,
                     adj_exp, atom_emb, Wt, bilinear_b, out);
}

// Round 8
// 204.174 us; speedup vs baseline: 1.1599x; 1.1599x over previous
//
#include <hip/hip_runtime.h>
#include <hip/hip_bf16.h>

#define N_ATOMS 2048
#define F_DIM   64
#define H_DIM   128
#define K_DIM   256
#define KD      8192
#define BM 64
#define BN 32
#define BK 128
#define NT (KD / BK)   // 64 K-steps

typedef __attribute__((ext_vector_type(8))) short short8;
typedef __attribute__((ext_vector_type(4))) float f32x4;
typedef __attribute__((ext_vector_type(8))) unsigned short ushort8v;

static __device__ __forceinline__ unsigned short f2bf(float x) {
  unsigned int u = __float_as_uint(x);
  u += 0x7fff + ((u >> 16) & 1);           // round-to-nearest-even
  return (unsigned short)(u >> 16);
}

// ---------------------------------------------------------------------------
// Fat kernel: blocks 0..2047 compute adj_exp rows (1 GiB nt stream, HBM-bound,
// dispatched FIRST); blocks 2048..2559 transpose+convert W into swizzled 8KB
// tiles (small, tail-fill).
// ---------------------------------------------------------------------------
__global__ __launch_bounds__(256) void fused_prep_kernel(
    const float* __restrict__ dist_adj,
    const float* __restrict__ dist_exp,
    const float* __restrict__ W,
    float* __restrict__ adj_exp,
    unsigned short* __restrict__ Wt) {
  __shared__ __align__(16) char smem[17408];
  const int t = threadIdx.x;

  if (blockIdx.x >= 2048) {
    // ---- wt path: 64 fh-rows x 64 cols per block ----
    const int q    = blockIdx.x - 2048;
    const int cb   = q >> 7;          // 0..3  (64-col group)
    const int kb   = (q >> 1) & 63;   // 0..63 (K-step)
    const int half = q & 1;           // fh half (64 rows)
    float (*tile)[68] = (float(*)[68])smem;

    {
      const int r0 = t >> 4;          // 0..15
      const int c4 = (t & 15) * 4;    // 0..60
      #pragma unroll
      for (int i = 0; i < 4; ++i) {
        const int r = i * 16 + r0;
        f32x4 v = *(const f32x4*)(W + (size_t)(kb * 128 + half * 64 + r) * K_DIM + cb * 64 + c4);
        tile[r][c4 + 0] = v[0]; tile[r][c4 + 1] = v[1];
        tile[r][c4 + 2] = v[2]; tile[r][c4 + 3] = v[3];
      }
    }
    __syncthreads();
    {
      char* outb = (char*)Wt;
      #pragma unroll
      for (int j = 0; j < 2; ++j) {
        const int lin  = t * 32 + j * 16;          // 0..8191
        const int cc   = lin >> 7;                 // 0..63 (col in 64-group)
        const int w128 = lin & 127;
        const int k0   = (w128 ^ ((cc & 7) << 4)) >> 1;   // local fh row (mult of 8)
        ushort8v v;
        #pragma unroll
        for (int e = 0; e < 8; ++e) v[e] = f2bf(tile[k0 + e][cc]);
        const size_t tb = (size_t)(((cb * 2 + (cc >> 5)) << 6) | kb) * 8192;
        *(ushort8v*)(outb + tb + (cc & 31) * 256 + half * 128 + w128) = v;
      }
    }
  } else {
    // ---- adj path (r6 verbatim): nt stream + scalar LDS coefficients ----
    const int m  = blockIdx.x;
    const int f4 = t & 15;
    const int ng = t >> 4;

    float* arowl = (float*)smem;                       // 8 KB
    f32x4* red   = (f32x4*)(smem + 8192);              // 4 KB

    {
      const f32x4* src = (const f32x4*)(dist_adj + (size_t)m * N_ATOMS);
      f32x4* dst = (f32x4*)arowl;
      #pragma unroll
      for (int i = 0; i < 2; ++i) {
        const int idx = i * 256 + t;
        dst[idx] = __builtin_nontemporal_load(src + idx);
      }
    }
    __syncthreads();

    const float* __restrict__ base = dist_exp + (size_t)m * N_ATOMS * F_DIM + f4 * 4;
    f32x4 acc = {0.f, 0.f, 0.f, 0.f};
    #pragma unroll 4
    for (int n = ng; n < N_ATOMS; n += 16) {
      float a  = arowl[n];
      f32x4 v = __builtin_nontemporal_load((const f32x4*)(base + (size_t)n * F_DIM));
      acc += a * v;
    }

    red[ng * 16 + f4] = acc;
    __syncthreads();
    if (t < 16) {
      f32x4 s = red[t];
      #pragma unroll
      for (int g = 1; g < 16; ++g) s += red[g * 16 + t];
      *(f32x4*)(adj_exp + m * F_DIM + t * 4) = s;
    }
  }
}

// ---------------------------------------------------------------------------
// Bilinear (UNCHANGED from r6): feat[m,c] = sum_f a[m,f] * (E . W_f)[m,c].
// BM=64 x BN=32; E in registers; 4-buffer depth-2 pipeline, one barrier/step.
// ---------------------------------------------------------------------------
__global__ __launch_bounds__(256) void bilinear_kernel(
    const float* __restrict__ adj_exp,         // [2048][64]
    const float* __restrict__ emb,             // [2048][128]
    const unsigned short* __restrict__ Wt,     // tiled swizzled bf16
    const float* __restrict__ bias,            // [256]
    float* __restrict__ out) {                 // [2048][256] f32
  const int b   = blockIdx.x;
  const int wg  = (b & 7) * 32 + (b >> 3);
  const int cbt = wg >> 5;       // 0..7 (32-col panel)
  const int mb  = wg & 31;       // 0..31
  const int m0  = mb * BM;
  const int c0  = cbt * BN;

  const int t  = threadIdx.x;
  const int w  = t >> 6;
  const int l  = t & 63;
  const int lr = l & 15;
  const int lg = l >> 4;
  const int cg = w & 1;
  const int rb = (w >> 1) * 32;

  __shared__ __align__(16) unsigned short Bl[4][4096];   // 4 x 8KB tiles
  __shared__ __align__(16) float adjT[F_DIM][BM];        // [f][m] 16KB

  const char* wt_base = (const char*)Wt;
  #define STAGE_B(buf, step)                                                      \
    {                                                                             \
      const char* src = wt_base + (size_t)((cbt << 6) | (step)) * 8192;           \
      char* dstb = (char*)&Bl[(buf)][0];                                          \
      _Pragma("unroll")                                                           \
      for (int i = 0; i < 2; ++i) {                                               \
        const int chunk = w * 2 + i;                                              \
        __builtin_amdgcn_global_load_lds(                                         \
            (const __attribute__((address_space(1))) unsigned int*)(src + chunk * 1024 + l * 16), \
            (__attribute__((address_space(3))) unsigned int*)(dstb + chunk * 1024), \
            16, 0, 0);                                                            \
      }                                                                           \
    }

  STAGE_B(0, 0);
  STAGE_B(1, 1);

  short8 Ef0[4], Ef1[4];
  {
    const float* p0 = emb + (size_t)(m0 + rb + lr) * H_DIM;
    const float* p1 = emb + (size_t)(m0 + rb + 16 + lr) * H_DIM;
    #pragma unroll
    for (int ks = 0; ks < 4; ++ks) {
      f32x4 u0 = *(const f32x4*)(p0 + ks * 32 + lg * 8);
      f32x4 u1 = *(const f32x4*)(p0 + ks * 32 + lg * 8 + 4);
      f32x4 v0 = *(const f32x4*)(p1 + ks * 32 + lg * 8);
      f32x4 v1 = *(const f32x4*)(p1 + ks * 32 + lg * 8 + 4);
      short8 e0, e1;
      #pragma unroll
      for (int i = 0; i < 4; ++i) {
        e0[i] = (short)f2bf(u0[i]); e0[4 + i] = (short)f2bf(u1[i]);
        e1[i] = (short)f2bf(v0[i]); e1[4 + i] = (short)f2bf(v1[i]);
      }
      Ef0[ks] = e0; Ef1[ks] = e1;
    }
  }
  {
    const int r  = t & 63;
    const int fb = (t >> 6) * 16;
    #pragma unroll
    for (int i = 0; i < 4; ++i) {
      f32x4 a = *(const f32x4*)(adj_exp + (size_t)(m0 + r) * F_DIM + fb + i * 4);
      adjT[fb + i * 4 + 0][r] = a[0]; adjT[fb + i * 4 + 1][r] = a[1];
      adjT[fb + i * 4 + 2][r] = a[2]; adjT[fb + i * 4 + 3][r] = a[3];
    }
  }
  __syncthreads();

  f32x4 facc0 = {0.f, 0.f, 0.f, 0.f};
  f32x4 facc1 = {0.f, 0.f, 0.f, 0.f};
  const int c_loc = cg * 16 + lr;
  const int bswz  = (lr & 7) << 4;

  #pragma unroll 1
  for (int ts = 0; ts < NT; ++ts) {
    if (ts + 2 < NT) {
      STAGE_B((ts + 2) & 3, ts + 2);
      asm volatile("s_waitcnt vmcnt(4)" ::: "memory");
    } else if (ts + 2 == NT) {
      asm volatile("s_waitcnt vmcnt(2)" ::: "memory");
    } else {
      asm volatile("s_waitcnt vmcnt(0)" ::: "memory");
    }
    __builtin_amdgcn_s_barrier();
    asm volatile("" ::: "memory");

    const char* Bbase = (const char*)&Bl[ts & 3][0];
    f32x4 t0 = {0.f, 0.f, 0.f, 0.f};
    f32x4 t1 = {0.f, 0.f, 0.f, 0.f};
    #pragma unroll
    for (int ks = 0; ks < 4; ++ks) {
      const int boff = c_loc * 256 + ((ks * 64 + lg * 16) ^ bswz);
      short8 bf = *(const short8*)(Bbase + boff);
      t0 = __builtin_amdgcn_mfma_f32_16x16x32_bf16(Ef0[ks], bf, t0, 0, 0, 0);
      t1 = __builtin_amdgcn_mfma_f32_16x16x32_bf16(Ef1[ks], bf, t1, 0, 0, 0);
    }
    f32x4 a0 = *(const f32x4*)&adjT[ts][rb + lg * 4];
    f32x4 a1 = *(const f32x4*)&adjT[ts][rb + 16 + lg * 4];
    facc0 += a0 * t0;
    facc1 += a1 * t1;
  }
  #undef STAGE_B

  const int col = c0 + c_loc;
  const float bb = bias[col];
  #pragma unroll
  for (int r = 0; r < 4; ++r) {
    const int row0 = m0 + rb + lg * 4 + r;
    float x0  = facc0[r];
    float sp0 = (x0 > 20.f) ? x0 : ((x0 < -20.f) ? __expf(x0) : log1pf(__expf(x0)));
    out[(size_t)row0 * K_DIM + col] = sp0 + bb;
    const int row1 = row0 + 16;
    float x1  = facc1[r];
    float sp1 = (x1 > 20.f) ? x1 : ((x1 < -20.f) ? __expf(x1) : log1pf(__expf(x1)));
    out[(size_t)row1 * K_DIM + col] = sp1 + bb;
  }
}

// ---------------------------------------------------------------------------
extern "C" void kernel_launch(void* const* d_in, const int* in_sizes, int n_in,
                              void* d_out, int out_size, void* d_ws, size_t ws_size,
                              hipStream_t stream) {
  const float* dist_adj   = (const float*)d_in[0];   // [2048][2048]
  const float* dist_exp   = (const float*)d_in[1];   // [2048][2048][64]
  const float* atom_emb   = (const float*)d_in[2];   // [2048][128]
  const float* bilinear_w = (const float*)d_in[3];   // [64][128][256]
  const float* bilinear_b = (const float*)d_in[4];   // [256]
  float* out = (float*)d_out;                        // f32 [2048][256]

  float* adj_exp = (float*)d_ws;                                   // 512 KB
  unsigned short* Wt =
      (unsigned short*)((char*)d_ws + (size_t)N_ATOMS * F_DIM * sizeof(float)); // 4 MB

  hipLaunchKernelGGL(fused_prep_kernel, dim3(N_ATOMS + 512), dim3(256), 0, stream,
                     dist_adj, dist_exp, bilinear_w, adj_exp, Wt);
  hipLaunchKernelGGL(bilinear_kernel, dim3((N_ATOMS / BM) * (K_DIM / BN)), dim3(256), 0, stream,
                     adj_exp, atom_emb, Wt, bilinear_b, out);
}